// Round 1
// baseline (442.212 us; speedup 1.0000x reference)
//
#include <hip/hip_runtime.h>

// Problem constants (B=8, Cin=O=16, group=12, H=64)
#define NB   8
#define NIC  192        // Cin*12
#define NOC  192        // O*12
#define HP   66
#define WP   322
#define HPWP (HP * WP)

typedef _Float16 f16x8 __attribute__((ext_vector_type(8)));
typedef float    f32x4 __attribute__((ext_vector_type(4)));

// Swizzled weights: [icc6][tap7][kg4][oc192][j8]  (516 KB) — L2-resident.
__device__ __align__(16) _Float16 g_Ks[6 * 7 * 4 * 192 * 8];
// Transposed f16 x: [b8][icc6][y66][col322][ic32]  (65.3 MB)
__device__ __align__(16) _Float16 g_xt[NB * 6 * 66 * 322 * 32];

// ---------------------------------------------------------------------------
// Kernel 1: expand weight (O,Cin,12,7) -> g_Ks (f16, MFMA-A-swizzled)
// ---------------------------------------------------------------------------
__global__ void prep_kernel(const float* __restrict__ w) {
    int tid = blockIdx.x * 256 + threadIdx.x;
    if (tid >= 7 * NOC * NIC) return;
    int ic = tid % NIC;
    int rest = tid / NIC;
    int oc = rest % NOC;
    int t = rest / NOC;
    int o = oc / 12, g = oc % 12;
    int c = ic / 12, h = ic % 12;
    int f = g / 6, r = g % 6;
    int ri = (f == 0) ? (6 - r) % 6 : r;          // inv(g).r
    int fh = h / 6, rh = h % 6;
    int pf = f ^ fh;
    int pr = (f == 0) ? (ri + rh) % 6 : (ri - rh + 6) % 6;
    int pm = pf * 6 + pr;                          // perm[g][h]
    const float* wsrc = w + ((o * 16 + c) * 12 + pm) * 7;
    float v;
    if (t == 0) {
        v = wsrc[0];
    } else {
        int i = t - 1;
        int s = (f == 0) ? (i - r + 6) % 6 : (r - i + 6) % 6;
        v = wsrc[1 + s];
    }
    int icc = ic >> 5, kg = (ic >> 3) & 3, j = ic & 7;
    g_Ks[((((icc * 7) + t) * 4 + kg) * 192 + oc) * 8 + j] = (_Float16)v;
}

// ---------------------------------------------------------------------------
// Kernel 2: LDS-tiled transpose x (fp32 [b][ic][y][col]) ->
//           g_xt (f16 [b][icc][y][col][ic32]).
// One block per (b, icc, y). Phase 1: wave-uniform channel, float2 along col
// (512 B contiguous per wave-instr). Phase 2: LDS-transposed read (pad 340,
// <=2-way conflicts), coalesced f16x8 global write (1 KB/wave-instr).
// ---------------------------------------------------------------------------
__global__ __launch_bounds__(256) void transpose_kernel(const float* __restrict__ x) {
    __shared__ __align__(16) _Float16 lt[32 * 340];   // [ic][colpad340], 21.8 KB

    int id  = blockIdx.x;                 // 8*6*66 = 3168 blocks
    int y   = id % 66;
    int icc = (id / 66) % 6;
    int b   = id / 396;

    int tid  = threadIdx.x;
    int icq  = tid >> 6;                  // 0..3 (wave index)
    int lane = tid & 63;

    const float* xb = x + (size_t)b * NIC * HPWP
                        + (size_t)(icc * 32) * HPWP
                        + (size_t)y * WP;

    // phase 1: 32 channels, 161 float2 col-pairs each
#pragma unroll
    for (int il = 0; il < 8; il++) {
        int ic = il * 4 + icq;
        const float* row = xb + (size_t)ic * HPWP;
#pragma unroll
        for (int c = 0; c < 3; c++) {
            int col2 = lane + c * 64;
            if (col2 < 161) {
                float2 v = *(const float2*)(row + col2 * 2);
                union { _Float16 h[2]; unsigned u; } p;
                p.h[0] = (_Float16)v.x;
                p.h[1] = (_Float16)v.y;
                *(unsigned*)&lt[ic * 340 + col2 * 2] = p.u;
            }
        }
    }
    __syncthreads();

    // phase 2: transpose out of LDS, coalesced writes
    int icg  = tid & 3;
    int colb = tid >> 2;                  // 0..63
    _Float16* dst = g_xt + (((size_t)b * 6 + icc) * 66 + y) * (322 * 32);
#pragma unroll
    for (int p = 0; p < 6; p++) {
        int col = colb + p * 64;
        if (col < 322) {
            union { f16x8 v8; _Float16 h[8]; } u;
#pragma unroll
            for (int j = 0; j < 8; j++)
                u.h[j] = lt[(icg * 8 + j) * 340 + col];
            *(f16x8*)&dst[col * 32 + icg * 8] = u.v8;
        }
    }
}

// ---------------------------------------------------------------------------
// Kernel 3: MFMA implicit-GEMM conv over 7 hex taps — barrier-free.
// Block C-tile: 192 oc x 128 px (2 rows x 64 cols). K chunk = 32 ic.
// A (weights) read directly from g_Ks (516 KB, L2-hot, coalesced 4x256B/wave);
// B (x) read directly from g_xt (coalesced dwordx4, L2-hot).
// No LDS, no __syncthreads -> occupancy is VGPR-bound only.
// Hex taps (hy,hx): 0:(1,1) 1:(0,0) 2:(0,1) 3:(1,2) 4:(2,2) 5:(2,1) 6:(1,0)
// ---------------------------------------------------------------------------
__global__ __launch_bounds__(256, 3) void conv_kernel(
    const float* __restrict__ bias, float* __restrict__ out) {
    int id = blockIdx.x;                  // 1280 blocks = 8 XCD * 160
    id = (id & 7) * 160 + (id >> 3);      // bijective XCD swizzle: XCD i owns b=i
    int xt5 = id % 5;
    int yt = (id / 5) % 32;
    int b  = id / 160;
    int px0 = xt5 * 64, py0 = yt * 2;

    int tid = threadIdx.x;
    int wave = tid >> 6;
    int lane = tid & 63;
    int kg = lane >> 4, n15 = lane & 15;
    int wm = wave & 1;                    // output row py0+1+wm
    int wn = wave >> 1;                   // oc half (wn*96)

    const int HY[7] = {1, 0, 0, 1, 2, 2, 1};
    const int HX[7] = {1, 0, 1, 2, 2, 1, 0};

    const _Float16* xtb = g_xt + (size_t)b * (6 * 66 * 322 * 32);

    f32x4 acc[6][4] = {};                 // [oc group][pixel group]

    for (int icc = 0; icc < 6; icc++) {
        const _Float16* xchunk = xtb + (size_t)icc * (66 * 322 * 32);
        const _Float16* kc = g_Ks + (size_t)icc * (7 * 4 * 192 * 8);

#pragma unroll
        for (int t = 0; t < 7; t++) {
            int row = py0 + wm + HY[t];
            const _Float16* bp = xchunk +
                ((size_t)row * 322 + px0 + HX[t] + n15) * 32 + kg * 8;
            f16x8 xf[4];
#pragma unroll
            for (int ni = 0; ni < 4; ni++)
                xf[ni] = *(const f16x8*)(bp + ni * (16 * 32));
#pragma unroll
            for (int mi = 0; mi < 6; mi++) {
                f16x8 wf = *(const f16x8*)
                    &kc[(((t * 4 + kg) * 192) + wn * 96 + mi * 16 + n15) * 8];
#pragma unroll
                for (int ni = 0; ni < 4; ni++)
                    acc[mi][ni] = __builtin_amdgcn_mfma_f32_16x16x32_f16(
                        wf, xf[ni], acc[mi][ni], 0, 0, 0);
            }
        }
    }

    // ---- epilogue: +bias, write interior rows ----
    int yo = py0 + 1 + wm;
#pragma unroll
    for (int mi = 0; mi < 6; mi++) {
#pragma unroll
        for (int reg = 0; reg < 4; reg++) {
            int oc = wn * 96 + mi * 16 + kg * 4 + reg;
            float bv = bias[oc / 12];
            size_t base = ((size_t)(b * NOC + oc) * HP + yo) * WP + 1 + px0 + n15;
#pragma unroll
            for (int ni = 0; ni < 4; ni++)
                out[base + ni * 16] = acc[mi][ni][reg] + bv;
        }
    }
}

// ---------------------------------------------------------------------------
// Kernel 4: fill the 1-px ring via twisted-periodic gather from interior.
// ---------------------------------------------------------------------------
__global__ void border_kernel(float* __restrict__ out) {
    int tid = blockIdx.x * 256 + threadIdx.x;   // < 8*192*772 = 1185792
    int r  = tid % 772;
    int bc = tid / 772;
    int ch = bc % NOC;
    int b  = bc / NOC;
    int y, xx;
    if (r < 322)      { y = 0;  xx = r; }
    else if (r < 644) { y = 65; xx = r - 322; }
    else if (r < 708) { xx = 0;   y = r - 644 + 1; }
    else              { xx = 321; y = r - 708 + 1; }
    int t = ch % 12;
    int o12 = ch - t;
    int f = t / 6, rr = t % 6;
    int dt = (xx == 0) ? 1 : ((xx == 321) ? -1 : 0);
    int sx = (xx == 0) ? 320 : ((xx == 321) ? 1 : xx);
    int sy = (y == 0) ? 64 : ((y == 65) ? 1 : y);
    int tsrc = f * 6 + (rr + dt + 6) % 6;
    float v = out[((size_t)(b * NOC + o12 + tsrc) * HP + sy) * WP + sx];
    out[((size_t)(b * NOC + ch) * HP + y) * WP + xx] = v;
}

extern "C" void kernel_launch(void* const* d_in, const int* in_sizes, int n_in,
                              void* d_out, int out_size, void* d_ws, size_t ws_size,
                              hipStream_t stream) {
    const float* x    = (const float*)d_in[0];
    const float* w    = (const float*)d_in[1];
    const float* bias = (const float*)d_in[2];
    float* out = (float*)d_out;

    prep_kernel<<<(7 * NOC * NIC + 255) / 256, 256, 0, stream>>>(w);
    transpose_kernel<<<NB * 6 * 66, 256, 0, stream>>>(x);
    conv_kernel<<<1280, 256, 0, stream>>>(bias, out);
    border_kernel<<<(NB * NOC * 772) / 256, 256, 0, stream>>>(out);
}

// Round 2
// 342.319 us; speedup vs baseline: 1.2918x; 1.2918x over previous
//
#include <hip/hip_runtime.h>

// Problem constants (B=8, Cin=O=16, group=12, H=64)
#define NB   8
#define NIC  192        // Cin*12
#define NOC  192        // O*12
#define HP   66
#define WP   322
#define HPWP (HP * WP)

typedef _Float16 f16x8 __attribute__((ext_vector_type(8)));
typedef float    f32x4 __attribute__((ext_vector_type(4)));

// Swizzled weights: [icc6][tap7][kg4][oc192][j8]  (516 KB) — L2-resident.
__device__ __align__(16) _Float16 g_Ks[6 * 7 * 4 * 192 * 8];
// Transposed f16 x: [b8][icc6][y66][kg4][col322][j8]  (65.3 MB)
__device__ __align__(16) _Float16 g_xt[NB * 6 * 66 * 4 * 322 * 8];

#define ICCH (66 * 4 * 322 * 8)   // halfs per (b,icc) slice of g_xt

// ---------------------------------------------------------------------------
// Kernel 1: expand weight (O,Cin,12,7) -> g_Ks (f16, MFMA-A-swizzled)
// ---------------------------------------------------------------------------
__global__ void prep_kernel(const float* __restrict__ w) {
    int tid = blockIdx.x * 256 + threadIdx.x;
    if (tid >= 7 * NOC * NIC) return;
    int ic = tid % NIC;
    int rest = tid / NIC;
    int oc = rest % NOC;
    int t = rest / NOC;
    int o = oc / 12, g = oc % 12;
    int c = ic / 12, h = ic % 12;
    int f = g / 6, r = g % 6;
    int ri = (f == 0) ? (6 - r) % 6 : r;          // inv(g).r
    int fh = h / 6, rh = h % 6;
    int pf = f ^ fh;
    int pr = (f == 0) ? (ri + rh) % 6 : (ri - rh + 6) % 6;
    int pm = pf * 6 + pr;                          // perm[g][h]
    const float* wsrc = w + ((o * 16 + c) * 12 + pm) * 7;
    float v;
    if (t == 0) {
        v = wsrc[0];
    } else {
        int i = t - 1;
        int s = (f == 0) ? (i - r + 6) % 6 : (r - i + 6) % 6;
        v = wsrc[1 + s];
    }
    int icc = ic >> 5, kg = (ic >> 3) & 3, j = ic & 7;
    g_Ks[((((icc * 7) + t) * 4 + kg) * 192 + oc) * 8 + j] = (_Float16)v;
}

// ---------------------------------------------------------------------------
// Kernel 2: transpose x (fp32 [b][ic][y][col]) -> g_xt [b][icc][y][kg][col][j8].
// Wave = one kg (8 channels); lane = column. Loads: 64 consecutive floats per
// plane per instr (256B). Stores: 64 lanes x 16B = 1KB contiguous. No LDS.
// ---------------------------------------------------------------------------
__global__ __launch_bounds__(256) void transpose_kernel(const float* __restrict__ x) {
    int id  = blockIdx.x;                 // 8*6*66 = 3168 blocks
    int y   = id % 66;
    int icc = (id / 66) % 6;
    int b   = id / 396;
    int kg   = threadIdx.x >> 6;
    int lane = threadIdx.x & 63;
    const float* src0 = x + ((size_t)b * NIC + icc * 32 + kg * 8) * HPWP + (size_t)y * WP;
    _Float16* dst = g_xt + ((((size_t)(b * 6 + icc) * 66 + y) * 4 + kg) * 322) * 8;
#pragma unroll
    for (int p = 0; p < 6; p++) {
        int col = lane + p * 64;
        if (p < 5 || col < 322) {
            union { f16x8 v8; _Float16 h[8]; } u;
#pragma unroll
            for (int j = 0; j < 8; j++)
                u.h[j] = (_Float16)src0[(size_t)j * HPWP + col];
            *(f16x8*)&dst[col * 8] = u.v8;
        }
    }
}

// ---------------------------------------------------------------------------
// Kernel 3: MFMA implicit-GEMM conv, software-pipelined LDS staging.
// A (weights): triple-buffered per-tap slabs (12.3KB), global_load_lds.
// B (x): double-buffered per-icc slab [row4][kg4][col66][j8] (+64-slot pad).
// One s_barrier per tap-step; counted vmcnt (3/8/0); setprio around MFMAs.
// Hex taps (hy,hx): 0:(1,1) 1:(0,0) 2:(0,1) 3:(1,2) 4:(2,2) 5:(2,1) 6:(1,0)
// ---------------------------------------------------------------------------
__device__ __forceinline__ void gload16(const _Float16* g, _Float16* l) {
    __builtin_amdgcn_global_load_lds(
        (const __attribute__((address_space(1))) void*)g,
        (__attribute__((address_space(3))) void*)l, 16, 0, 0);
}

__global__ __launch_bounds__(256, 2) void conv_kernel(
    const float* __restrict__ bias, float* __restrict__ out) {
    __shared__ __align__(16) _Float16 lA[3][6144];   // 3 x 12,288B tap slabs
    __shared__ __align__(16) _Float16 lB[2][8960];   // 2 x 17,920B (1056+64 pad slots)

    int id = blockIdx.x;                  // 1280 blocks = 8 XCD * 160
    id = (id & 7) * 160 + (id >> 3);      // bijective XCD swizzle: XCD i owns b=i
    int xt5 = id % 5;
    int yt = (id / 5) % 32;
    int b  = id / 160;
    int px0 = xt5 * 64, py0 = yt * 2;

    int tid = threadIdx.x;
    int wave = tid >> 6;
    int lane = tid & 63;
    int kg = lane >> 4, n15 = lane & 15;
    int wm = wave & 1;                    // output row py0+1+wm
    int wn = wave >> 1;                   // oc half (wn*96)

    const _Float16* xtb = g_xt + (size_t)b * (6 * ICCH);

    // Precompute B-stage slot decompositions (icc-invariant). 5 uniform issues.
    int gbo[5], lso[5];
#pragma unroll
    for (int k = 0; k < 5; k++) {
        int slot = tid + k * 256;
        if (slot > 1055) slot = 1055;     // clamp: pad region absorbs overflow
        int row = slot / 264;
        int rem = slot % 264;
        int kg2 = rem / 66;
        int col = rem % 66;
        gbo[k] = (((py0 + row) * 4 + kg2) * 322 + px0 + col) * 8;
        lso[k] = slot * 8;
    }

    f32x4 acc[6][4] = {};                 // [oc group][pixel group]

#define WV3 asm volatile("s_waitcnt vmcnt(3)" ::: "memory")
#define WV8 asm volatile("s_waitcnt vmcnt(8)" ::: "memory")
#define WV0 asm volatile("s_waitcnt vmcnt(0)" ::: "memory")

#define COMPUTE(T, HYv, HXv)                                                   \
    {                                                                          \
        const _Float16* bb = &lB[bi][(((wm + (HYv)) * 4 + kg) * 66 +           \
                                      (HXv) + n15) * 8];                       \
        f16x8 xf[4];                                                           \
        _Pragma("unroll")                                                      \
        for (int ni = 0; ni < 4; ni++)                                         \
            xf[ni] = *(const f16x8*)(bb + ni * (16 * 8));                      \
        __builtin_amdgcn_s_setprio(1);                                         \
        _Pragma("unroll")                                                      \
        for (int mi = 0; mi < 6; mi++) {                                       \
            f16x8 wf = *(const f16x8*)                                         \
                &lA[IA(T)][(kg * 192 + wn * 96 + mi * 16 + n15) * 8];          \
            _Pragma("unroll")                                                  \
            for (int ni = 0; ni < 4; ni++)                                     \
                acc[mi][ni] = __builtin_amdgcn_mfma_f32_16x16x32_f16(          \
                    wf, xf[ni], acc[mi][ni], 0, 0, 0);                         \
        }                                                                      \
        __builtin_amdgcn_s_setprio(0);                                         \
    }

#define STEP(T, WVBLK, HYv, HXv)                                               \
    {                                                                          \
        if ((T) < 6 || icc < 5) {  /* stage A for next tap-step */             \
            const _Float16* asrc = kb + ((T) + 1) * 6144;                      \
            gload16(asrc + (tid + 0 * 256) * 8,                                \
                    &lA[JA(T)][(tid + 0 * 256) * 8]);                          \
            gload16(asrc + (tid + 1 * 256) * 8,                                \
                    &lA[JA(T)][(tid + 1 * 256) * 8]);                          \
            gload16(asrc + (tid + 2 * 256) * 8,                                \
                    &lA[JA(T)][(tid + 2 * 256) * 8]);                          \
        }                                                                      \
        WVBLK;                                                                 \
        __builtin_amdgcn_s_barrier();                                          \
        __builtin_amdgcn_sched_barrier(0);                                     \
        if ((T) == 4 && icc < 5) {  /* stage B for next icc */                 \
            const _Float16* bsrc = xtb + (size_t)(icc + 1) * ICCH;             \
            gload16(bsrc + gbo[0], &lB[bi ^ 1][lso[0]]);                       \
            gload16(bsrc + gbo[1], &lB[bi ^ 1][lso[1]]);                       \
            gload16(bsrc + gbo[2], &lB[bi ^ 1][lso[2]]);                       \
            gload16(bsrc + gbo[3], &lB[bi ^ 1][lso[3]]);                       \
            gload16(bsrc + gbo[4], &lB[bi ^ 1][lso[4]]);                       \
        }                                                                      \
        COMPUTE(T, HYv, HXv);                                                  \
    }

    // A-buffer rotation: step t uses buf (ia0+t)%3, stages into (ia0+t+1)%3.
    int ia0 = 0, ia1 = 1, ia2 = 2;
    int bi = 0;
#define IA(T) ((T) == 0 || (T) == 3 || (T) == 6 ? ia0 : ((T) == 1 || (T) == 4 ? ia1 : ia2))
#define JA(T) IA((T) + 1 > 6 ? 0 : (T) + 1)  // placeholder, overridden below
#undef JA
#define JA(T) ((T) == 2 || (T) == 5 ? ia0 : ((T) == 0 || (T) == 3 || (T) == 6 ? ia1 : ia2))

    // Prologue: B[0] first (so t0's vmcnt(3) covers it), then A[icc0,tap0].
    {
        const _Float16* bsrc = xtb;
        gload16(bsrc + gbo[0], &lB[0][lso[0]]);
        gload16(bsrc + gbo[1], &lB[0][lso[1]]);
        gload16(bsrc + gbo[2], &lB[0][lso[2]]);
        gload16(bsrc + gbo[3], &lB[0][lso[3]]);
        gload16(bsrc + gbo[4], &lB[0][lso[4]]);
        const _Float16* asrc = g_Ks;
        gload16(asrc + (tid + 0 * 256) * 8, &lA[0][(tid + 0 * 256) * 8]);
        gload16(asrc + (tid + 1 * 256) * 8, &lA[0][(tid + 1 * 256) * 8]);
        gload16(asrc + (tid + 2 * 256) * 8, &lA[0][(tid + 2 * 256) * 8]);
    }

    for (int icc = 0; icc < 6; icc++) {
        const _Float16* kb = g_Ks + icc * (7 * 6144);
        STEP(0, WV3, 1, 1);
        STEP(1, WV3, 0, 0);
        STEP(2, WV3, 0, 1);
        STEP(3, WV3, 1, 2);
        STEP(4, WV3, 2, 2);
        STEP(5, { if (icc < 5) { WV8; } else { WV3; } }, 2, 1);
        STEP(6, { if (icc < 5) { WV3; } else { WV0; } }, 1, 0);
        { int tt = ia0; ia0 = ia1; ia1 = ia2; ia2 = tt; }
        bi ^= 1;
    }
#undef STEP
#undef COMPUTE
#undef IA
#undef JA

    // ---- epilogue: +bias, write interior rows ----
    int yo = py0 + 1 + wm;
#pragma unroll
    for (int mi = 0; mi < 6; mi++) {
#pragma unroll
        for (int reg = 0; reg < 4; reg++) {
            int oc = wn * 96 + mi * 16 + kg * 4 + reg;
            float bv = bias[oc / 12];
            size_t base = ((size_t)(b * NOC + oc) * HP + yo) * WP + 1 + px0 + n15;
#pragma unroll
            for (int ni = 0; ni < 4; ni++)
                out[base + ni * 16] = acc[mi][ni][reg] + bv;
        }
    }
}

// ---------------------------------------------------------------------------
// Kernel 4: fill the 1-px ring via twisted-periodic gather from interior.
// ---------------------------------------------------------------------------
__global__ void border_kernel(float* __restrict__ out) {
    int tid = blockIdx.x * 256 + threadIdx.x;   // < 8*192*772 = 1185792
    int r  = tid % 772;
    int bc = tid / 772;
    int ch = bc % NOC;
    int b  = bc / NOC;
    int y, xx;
    if (r < 322)      { y = 0;  xx = r; }
    else if (r < 644) { y = 65; xx = r - 322; }
    else if (r < 708) { xx = 0;   y = r - 644 + 1; }
    else              { xx = 321; y = r - 708 + 1; }
    int t = ch % 12;
    int o12 = ch - t;
    int f = t / 6, rr = t % 6;
    int dt = (xx == 0) ? 1 : ((xx == 321) ? -1 : 0);
    int sx = (xx == 0) ? 320 : ((xx == 321) ? 1 : xx);
    int sy = (y == 0) ? 64 : ((y == 65) ? 1 : y);
    int tsrc = f * 6 + (rr + dt + 6) % 6;
    float v = out[((size_t)(b * NOC + o12 + tsrc) * HP + sy) * WP + sx];
    out[((size_t)(b * NOC + ch) * HP + y) * WP + xx] = v;
}

extern "C" void kernel_launch(void* const* d_in, const int* in_sizes, int n_in,
                              void* d_out, int out_size, void* d_ws, size_t ws_size,
                              hipStream_t stream) {
    const float* x    = (const float*)d_in[0];
    const float* w    = (const float*)d_in[1];
    const float* bias = (const float*)d_in[2];
    float* out = (float*)d_out;

    prep_kernel<<<(7 * NOC * NIC + 255) / 256, 256, 0, stream>>>(w);
    transpose_kernel<<<NB * 6 * 66, 256, 0, stream>>>(x);
    conv_kernel<<<1280, 256, 0, stream>>>(bias, out);
    border_kernel<<<(NB * NOC * 772) / 256, 256, 0, stream>>>(out);
}